// Round 5
// baseline (38009.647 us; speedup 1.0000x reference)
//
#include <hip/hip_runtime.h>
#include <math.h>

#define NB 512      // batch
#define NT 512      // time
#define NCTRL 256
#define NWORD 128
#define NMEM 128
#define NDIN 64
#define NACT 448    // x(64) | read(128) | ctrl(256)
#define G 4         // batch rows per workgroup
#define EPSF 1e-6f

// fp32 workspace layout (element offsets) — unchanged from round 4
#define OFF_WA   0        // [448][512]  fused r,z weights (transposed)
#define OFF_WNI  229376   // [192][256]  W_ih rows 512..767 transposed (inn)
#define OFF_WNH  278528   // [256][256]  W_hh rows 512..767 transposed (hn)
#define OFF_WH   344064   // [256][512]  heads: key|erase|add|beta|pad (transposed)
#define OFF_BA   475136   // [512]  b_ih[j]+b_hh[j]
#define OFF_BNI  475648   // [256]  b_ih[512+i]
#define OFF_BNH  475904   // [256]  b_hh[512+i]
#define OFF_BH   476160   // [512]  [b_key|b_erase|b_add|b_beta|0]
#define WS_FLOATS 476672

__device__ __forceinline__ float sigf(float x) { return 1.0f / (1.0f + expf(-x)); }
__device__ __forceinline__ float softplusf(float x) {
    return (x > 15.0f) ? x : log1pf(expf(x));
}

__global__ __launch_bounds__(256) void prep_kernel(
    const float* __restrict__ Wih, const float* __restrict__ bih,
    const float* __restrict__ Whh, const float* __restrict__ bhh,
    const float* __restrict__ Wkey, const float* __restrict__ bkey,
    const float* __restrict__ Wbeta, const float* __restrict__ bbeta,
    const float* __restrict__ Wer, const float* __restrict__ ber,
    const float* __restrict__ Wadd, const float* __restrict__ badd,
    float* __restrict__ ws)
{
    int i = blockIdx.x * 256 + threadIdx.x;
    if (i >= WS_FLOATS) return;
    float v;
    if (i < OFF_WNI) {                       // WA_T [448][512]
        int k = i >> 9, j = i & 511;
        v = (k < 192) ? Wih[j * 192 + k] : Whh[j * 256 + (k - 192)];
    } else if (i < OFF_WNH) {                // WNI_T [192][256]
        int i2 = i - OFF_WNI; int k = i2 >> 8, c = i2 & 255;
        v = Wih[(512 + c) * 192 + k];
    } else if (i < OFF_WH) {                 // WNH_T [256][256]
        int i2 = i - OFF_WNH; int k = i2 >> 8, c = i2 & 255;
        v = Whh[(512 + c) * 256 + k];
    } else if (i < OFF_BA) {                 // WH_T [256][512]
        int i2 = i - OFF_WH; int k = i2 >> 9, c = i2 & 511;
        if (c < 128)       v = Wkey[c * 256 + k];
        else if (c < 256)  v = Wer[(c - 128) * 256 + k];
        else if (c < 384)  v = Wadd[(c - 256) * 256 + k];
        else if (c == 384) v = Wbeta[k];
        else               v = 0.0f;
    } else if (i < OFF_BNI) {
        int j = i - OFF_BA;
        v = bih[j] + bhh[j];
    } else if (i < OFF_BNH) {
        v = bih[512 + (i - OFF_BNI)];
    } else if (i < OFF_BH) {
        v = bhh[512 + (i - OFF_BNH)];
    } else {
        int c = i - OFF_BH;
        if (c < 128)       v = bkey[c];
        else if (c < 256)  v = ber[c - 128];
        else if (c < 384)  v = badd[c - 256];
        else if (c == 384) v = bbeta[0];
        else               v = 0.0f;
    }
    ws[i] = v;
}

// G=4 rows per 256-thread WG. M lives in VGPRs: wave w owns batch-row w's M,
// lane ln holds memory-rows (ln, ln+64) = 2x128 floats. Weights stream once
// per WG-step from L2, shared by 4 rows. 1 WG/CU (VGPR-bound), 128 WGs.
__global__ __launch_bounds__(256, 1) void ntm4(
    const float* __restrict__ data, const int* __restrict__ batch_sizes,
    const int* __restrict__ unsort, const float* __restrict__ M0,
    const float* __restrict__ ws, float* __restrict__ out)
{
    __shared__ float act[G][NACT];                 // [x | read | ctrl]
    __shared__ float keyv[G][NWORD], ev_s[G][NWORD], av_s[G][NWORD], readv[G][NWORD];
    __shared__ float beta_sh[G];
    __shared__ float P[G][64][36];                 // read-reduction staging (36: 16B-aligned rows)
    __shared__ int len_sh[G], slot_sh[G];

    const int tid = threadIdx.x;
    const int wv = tid >> 6, ln = tid & 63;
    const int b0 = blockIdx.x * G;                 // packed rows b0..b0+3 (similar lengths)

    if (tid < G) len_sh[tid] = 0;
    __syncthreads();
    {
        int s0 = batch_sizes[tid], s1 = batch_sizes[tid + 256];
        int u0 = unsort[tid], u1 = unsort[tid + 256];
        #pragma unroll
        for (int g = 0; g < G; ++g) {
            int bg = b0 + g;
            int c = (s0 > bg) + (s1 > bg);
            if (c) atomicAdd(&len_sh[g], c);
            if (u0 == bg) slot_sh[g] = tid;        // inverse permutation
            if (u1 == bg) slot_sh[g] = tid + 256;
        }
    }
    #pragma unroll
    for (int g = 0; g < G; ++g) act[g][192 + tid] = 0.0f;   // ctrl = 0
    readv[wv][ln] = 0.0f;
    readv[wv][64 + ln] = 0.0f;
    __syncthreads();

    int lenr[G];
    #pragma unroll
    for (int g = 0; g < G; ++g) lenr[g] = len_sh[g];
    const int lenmax = lenr[0];                    // packed order: row b0 is longest

    // ---- M0 -> registers (one-time; same init for every row)
    float Mreg[2][NWORD];
    #pragma unroll
    for (int h = 0; h < 2; ++h) {
        const float* src = M0 + (ln + 64 * h) * NWORD;
        #pragma unroll
        for (int c = 0; c < NWORD; c += 4) {
            float4 v = *(const float4*)(src + c);
            Mreg[h][c] = v.x; Mreg[h][c + 1] = v.y;
            Mreg[h][c + 2] = v.z; Mreg[h][c + 3] = v.w;
        }
    }

    const float bA0 = ws[OFF_BA + tid],  bA1 = ws[OFF_BA + 256 + tid];
    const float bNi = ws[OFF_BNI + tid], bNh = ws[OFF_BNH + tid];
    const float bH0 = ws[OFF_BH + tid],  bH1 = ws[OFF_BH + 256 + tid];

    for (int t = 0; t < lenmax; ++t) {
        // ---- stage x and read into act (ctrl region already holds ctrl_{t-1})
        act[wv][ln] = data[((long)t * NB + (b0 + wv)) * NDIN + ln];
        act[wv][64 + ln]  = readv[wv][ln];
        act[wv][128 + ln] = readv[wv][64 + ln];
        __syncthreads();

        // ---- fused r,z GEMV: thread -> cols (tid, tid+256), all 4 rows
        float accr[G], accz[G];
        #pragma unroll
        for (int g = 0; g < G; ++g) { accr[g] = bA0; accz[g] = bA1; }
        {
            const float* wa = ws + OFF_WA + tid;
            for (int k = 0; k < NACT; k += 4) {
                float4 a0 = *(const float4*)&act[0][k];
                float4 a1 = *(const float4*)&act[1][k];
                float4 a2 = *(const float4*)&act[2][k];
                float4 a3 = *(const float4*)&act[3][k];
#define RZ_STEP(COMP, I) { \
                float w0 = wa[(k + I) * 512], w1 = wa[(k + I) * 512 + 256]; \
                accr[0] = fmaf(a0.COMP, w0, accr[0]); accz[0] = fmaf(a0.COMP, w1, accz[0]); \
                accr[1] = fmaf(a1.COMP, w0, accr[1]); accz[1] = fmaf(a1.COMP, w1, accz[1]); \
                accr[2] = fmaf(a2.COMP, w0, accr[2]); accz[2] = fmaf(a2.COMP, w1, accz[2]); \
                accr[3] = fmaf(a3.COMP, w0, accr[3]); accz[3] = fmaf(a3.COMP, w1, accz[3]); }
                RZ_STEP(x, 0) RZ_STEP(y, 1) RZ_STEP(z, 2) RZ_STEP(w, 3)
#undef RZ_STEP
            }
        }
        // ---- inn (k<192) and hn (k<256) GEMVs: thread -> col tid, all rows
        float acci[G], acch[G];
        #pragma unroll
        for (int g = 0; g < G; ++g) { acci[g] = bNi; acch[g] = bNh; }
        {
            const float* wi = ws + OFF_WNI + tid;
            for (int k = 0; k < 192; k += 4) {
                float4 a0 = *(const float4*)&act[0][k];
                float4 a1 = *(const float4*)&act[1][k];
                float4 a2 = *(const float4*)&act[2][k];
                float4 a3 = *(const float4*)&act[3][k];
#define NI_STEP(COMP, I) { \
                float w0 = wi[(k + I) * 256]; \
                acci[0] = fmaf(a0.COMP, w0, acci[0]); acci[1] = fmaf(a1.COMP, w0, acci[1]); \
                acci[2] = fmaf(a2.COMP, w0, acci[2]); acci[3] = fmaf(a3.COMP, w0, acci[3]); }
                NI_STEP(x, 0) NI_STEP(y, 1) NI_STEP(z, 2) NI_STEP(w, 3)
#undef NI_STEP
            }
            const float* wh = ws + OFF_WNH + tid;
            for (int k = 0; k < 256; k += 4) {
                float4 a0 = *(const float4*)&act[0][192 + k];
                float4 a1 = *(const float4*)&act[1][192 + k];
                float4 a2 = *(const float4*)&act[2][192 + k];
                float4 a3 = *(const float4*)&act[3][192 + k];
#define NH_STEP(COMP, I) { \
                float w0 = wh[(k + I) * 256]; \
                acch[0] = fmaf(a0.COMP, w0, acch[0]); acch[1] = fmaf(a1.COMP, w0, acch[1]); \
                acch[2] = fmaf(a2.COMP, w0, acch[2]); acch[3] = fmaf(a3.COMP, w0, acch[3]); }
                NH_STEP(x, 0) NH_STEP(y, 1) NH_STEP(z, 2) NH_STEP(w, 3)
#undef NH_STEP
            }
        }
        // ---- GRU combine (read old ctrl BEFORE overwrite)
        float cnew[G];
        #pragma unroll
        for (int g = 0; g < G; ++g) {
            float rg = sigf(accr[g]), zg = sigf(accz[g]);
            float ng = tanhf(fmaf(rg, acch[g], acci[g]));
            float cold = act[g][192 + tid];
            cnew[g] = fmaf(zg, cold - ng, ng);
        }
        __syncthreads();
        #pragma unroll
        for (int g = 0; g < G; ++g)
            if (t < lenr[g]) act[g][192 + tid] = cnew[g];   // frozen rows keep final ctrl
        __syncthreads();

        // ---- heads GEMV: cols (tid, tid+256) of [key|erase|add|beta|pad]
        float h0a[G], h1a[G];
        #pragma unroll
        for (int g = 0; g < G; ++g) { h0a[g] = bH0; h1a[g] = bH1; }
        {
            const float* wh = ws + OFF_WH + tid;
            for (int k = 0; k < 256; k += 4) {
                float4 a0 = *(const float4*)&act[0][192 + k];
                float4 a1 = *(const float4*)&act[1][192 + k];
                float4 a2 = *(const float4*)&act[2][192 + k];
                float4 a3 = *(const float4*)&act[3][192 + k];
#define HD_STEP(COMP, I) { \
                float w0 = wh[(k + I) * 512], w1 = wh[(k + I) * 512 + 256]; \
                h0a[0] = fmaf(a0.COMP, w0, h0a[0]); h1a[0] = fmaf(a0.COMP, w1, h1a[0]); \
                h0a[1] = fmaf(a1.COMP, w0, h0a[1]); h1a[1] = fmaf(a1.COMP, w1, h1a[1]); \
                h0a[2] = fmaf(a2.COMP, w0, h0a[2]); h1a[2] = fmaf(a2.COMP, w1, h1a[2]); \
                h0a[3] = fmaf(a3.COMP, w0, h0a[3]); h1a[3] = fmaf(a3.COMP, w1, h1a[3]); }
                HD_STEP(x, 0) HD_STEP(y, 1) HD_STEP(z, 2) HD_STEP(w, 3)
#undef HD_STEP
            }
        }
        #pragma unroll
        for (int g = 0; g < G; ++g) {
            if (tid < 128) { keyv[g][tid] = tanhf(h0a[g]); av_s[g][tid] = h1a[g]; }
            else           { ev_s[g][tid - 128] = sigf(h0a[g]); }
            if (tid == 128) beta_sh[g] = softplusf(h1a[g]);   // col 384
        }
        __syncthreads();

        // ---- memory module: wave wv serves row wv, fully wave-local
        if (t < lenr[wv]) {                        // wave-uniform guard (no barriers inside)
            float kx = keyv[wv][ln], ky = keyv[wv][64 + ln];
            float s = kx * kx + ky * ky;
            #pragma unroll
            for (int o = 32; o >= 1; o >>= 1) s += __shfl_xor(s, o);
            const float inv_nk = 1.0f / (sqrtf(s) + EPSF);

            float dot0 = 0.f, nn0 = 0.f, dot1 = 0.f, nn1 = 0.f;
            #pragma unroll
            for (int c = 0; c < NWORD; c += 4) {
                float4 k4 = *(const float4*)&keyv[wv][c];
#define COS_STEP(COMP, I) { \
                float m0 = Mreg[0][c + I], m1 = Mreg[1][c + I]; \
                dot0 = fmaf(m0, k4.COMP, dot0); nn0 = fmaf(m0, m0, nn0); \
                dot1 = fmaf(m1, k4.COMP, dot1); nn1 = fmaf(m1, m1, nn1); }
                COS_STEP(x, 0) COS_STEP(y, 1) COS_STEP(z, 2) COS_STEP(w, 3)
#undef COS_STEP
            }
            const float beta = beta_sh[wv];
            float l0 = beta * (dot0 * inv_nk / (sqrtf(nn0) + EPSF));
            float l1 = beta * (dot1 * inv_nk / (sqrtf(nn1) + EPSF));
            float mx = fmaxf(l0, l1);
            #pragma unroll
            for (int o = 32; o >= 1; o >>= 1) mx = fmaxf(mx, __shfl_xor(mx, o));
            float e0 = expf(l0 - mx), e1 = expf(l1 - mx);
            float es = e0 + e1;
            #pragma unroll
            for (int o = 32; o >= 1; o >>= 1) es += __shfl_xor(es, o);
            const float w0 = e0 / es, w1 = e1 / es;  // softmax weights, rows ln, ln+64

            // read vector: p = w0*M[ln] + w1*M[ln+64], column-summed over lanes
            const int cc = ln & 31, h2 = ln >> 5;
            #pragma unroll
            for (int ch = 0; ch < 4; ++ch) {
                asm volatile("s_waitcnt lgkmcnt(0)" ::: "memory");
                #pragma unroll
                for (int c2 = 0; c2 < 32; c2 += 4) {
                    const int c = ch * 32 + c2;
                    float4 pv;
                    pv.x = fmaf(w0, Mreg[0][c],     w1 * Mreg[1][c]);
                    pv.y = fmaf(w0, Mreg[0][c + 1], w1 * Mreg[1][c + 1]);
                    pv.z = fmaf(w0, Mreg[0][c + 2], w1 * Mreg[1][c + 2]);
                    pv.w = fmaf(w0, Mreg[0][c + 3], w1 * Mreg[1][c + 3]);
                    *(float4*)&P[wv][ln][c2] = pv;
                }
                asm volatile("s_waitcnt lgkmcnt(0)" ::: "memory");
                float s0 = 0.f, s1 = 0.f;
                #pragma unroll
                for (int i = 0; i < 32; i += 2) {
                    s0 += P[wv][h2 * 32 + i][cc];
                    s1 += P[wv][h2 * 32 + i + 1][cc];
                }
                float ssum = s0 + s1;
                ssum += __shfl_xor(ssum, 32);        // combine the two lane-halves
                if (h2 == 0) readv[wv][ch * 32 + cc] = ssum;
            }

            // update: M = M - w*(e*M - a)
            #pragma unroll
            for (int c = 0; c < NWORD; c += 4) {
                float4 e4 = *(const float4*)&ev_s[wv][c];
                float4 a4 = *(const float4*)&av_s[wv][c];
#define UPD(H, WSEL, COMP, I) { \
                float m = Mreg[H][c + I]; \
                float tt = fmaf(e4.COMP, m, -a4.COMP); \
                Mreg[H][c + I] = fmaf(-(WSEL), tt, m); }
                UPD(0, w0, x, 0) UPD(0, w0, y, 1) UPD(0, w0, z, 2) UPD(0, w0, w, 3)
                UPD(1, w1, x, 0) UPD(1, w1, y, 1) UPD(1, w1, z, 2) UPD(1, w1, w, 3)
#undef UPD
            }
        }
        __syncthreads();
    }

    #pragma unroll
    for (int g = 0; g < G; ++g) {
        const int s = slot_sh[g];
        out[(long)s * NCTRL + tid] = act[g][192 + tid];
        if (tid < NWORD) out[(long)NB * NCTRL + (long)s * NWORD + tid] = readv[g][tid];
    }
}

// FALLBACK (ws too small): round-4 verified slow path, unchanged.
__global__ __launch_bounds__(256) void ntm_slow(
    const float* __restrict__ data, const int* __restrict__ batch_sizes,
    const int* __restrict__ unsort,
    const float* __restrict__ Wih, const float* __restrict__ bih,
    const float* __restrict__ Whh, const float* __restrict__ bhh,
    const float* __restrict__ Wkey, const float* __restrict__ bkey,
    const float* __restrict__ Wbeta, const float* __restrict__ bbeta,
    const float* __restrict__ Wer, const float* __restrict__ ber,
    const float* __restrict__ Wadd, const float* __restrict__ badd,
    const float* __restrict__ M0, float* __restrict__ out)
{
    __shared__ float M[NMEM][NWORD + 1];
    __shared__ float act[NACT];
    __shared__ float ctrlB[NCTRL];
    __shared__ float gpre[512], ginn[256], ghn[256], hpre[448];
    __shared__ float readv[NWORD], keyv[NWORD], ev[NWORD], av[NWORD];
    __shared__ float cosb[NMEM], wb[NMEM], part[2 * NWORD], scal[2];
    __shared__ int len_sh;

    const int tid = threadIdx.x;
    const int g = blockIdx.x;
    const int b = unsort[g];

    if (tid == 0) {
        int L = 0;
        for (int t = 0; t < NT; ++t) L += (batch_sizes[t] > b);
        len_sh = L;
    }
    for (int i = tid; i < NMEM * NWORD; i += 256)
        M[i >> 7][i & 127] = M0[i];
    ctrlB[tid] = 0.0f;
    if (tid < NWORD) readv[tid] = 0.0f;
    __syncthreads();
    const int len = len_sh;
    const int wave = tid >> 6, lane = tid & 63;

    for (int t = 0; t < len; ++t) {
        if (tid < 64)  act[tid] = data[((long)t * NB + b) * NDIN + tid];
        if (tid < 128) act[64 + tid] = readv[tid];
        act[192 + tid] = ctrlB[tid];
        __syncthreads();

        for (int j = wave; j < 512; j += 4) {
            float p = 0.f;
            for (int k = lane; k < 192; k += 64) p = fmaf(act[k], Wih[j * 192 + k], p);
            for (int k = lane; k < 256; k += 64) p = fmaf(act[192 + k], Whh[j * 256 + k], p);
            #pragma unroll
            for (int o = 32; o >= 1; o >>= 1) p += __shfl_xor(p, o);
            if (lane == 0) gpre[j] = p;
        }
        for (int j = wave; j < 256; j += 4) {
            float pi = 0.f, ph = 0.f;
            for (int k = lane; k < 192; k += 64) pi = fmaf(act[k], Wih[(512 + j) * 192 + k], pi);
            for (int k = lane; k < 256; k += 64) ph = fmaf(act[192 + k], Whh[(512 + j) * 256 + k], ph);
            #pragma unroll
            for (int o = 32; o >= 1; o >>= 1) { pi += __shfl_xor(pi, o); ph += __shfl_xor(ph, o); }
            if (lane == 0) { ginn[j] = pi; ghn[j] = ph; }
        }
        __syncthreads();
        {
            float r = sigf(gpre[tid] + bih[tid] + bhh[tid]);
            float z = sigf(gpre[256 + tid] + bih[256 + tid] + bhh[256 + tid]);
            float inn = ginn[tid] + bih[512 + tid];
            float hn  = ghn[tid] + bhh[512 + tid];
            float n = tanhf(fmaf(r, hn, inn));
            float cold = act[192 + tid];
            ctrlB[tid] = fmaf(z, cold - n, n);
        }
        __syncthreads();
        for (int j = wave; j < 385; j += 4) {
            const float* Wp; long base;
            if (j < 128)      { Wp = Wkey;  base = (long)j * 256; }
            else if (j < 256) { Wp = Wer;   base = (long)(j - 128) * 256; }
            else if (j < 384) { Wp = Wadd;  base = (long)(j - 256) * 256; }
            else              { Wp = Wbeta; base = 0; }
            float p = 0.f;
            for (int k = lane; k < 256; k += 64) p = fmaf(ctrlB[k], Wp[base + k], p);
            #pragma unroll
            for (int o = 32; o >= 1; o >>= 1) p += __shfl_xor(p, o);
            if (lane == 0) hpre[j] = p;
        }
        __syncthreads();
        if (tid < 128) {
            keyv[tid] = tanhf(hpre[tid] + bkey[tid]);
            ev[tid]   = sigf(hpre[128 + tid] + ber[tid]);
            av[tid]   = hpre[256 + tid] + badd[tid];
        }
        if (tid == 0) scal[1] = softplusf(hpre[384] + bbeta[0]);
        __syncthreads();

        if (tid < 64) {
            float s = keyv[tid] * keyv[tid] + keyv[tid + 64] * keyv[tid + 64];
            #pragma unroll
            for (int o = 32; o >= 1; o >>= 1) s += __shfl_xor(s, o);
            if (tid == 0) scal[0] = 1.0f / (sqrtf(s) + EPSF);
        }
        __syncthreads();
        {
            int rr = tid >> 1, hh = tid & 1;
            const float* Mr = &M[rr][hh * 64];
            const float* kk = keyv + hh * 64;
            float s2 = 0.f, sc = 0.f;
            #pragma unroll 8
            for (int j = 0; j < 64; ++j) { float m = Mr[j]; s2 = fmaf(m, m, s2); sc = fmaf(m, kk[j], sc); }
            s2 += __shfl_xor(s2, 1);
            sc += __shfl_xor(sc, 1);
            if (hh == 0) cosb[rr] = sc * scal[0] / (sqrtf(s2) + EPSF);
        }
        __syncthreads();
        if (tid < 64) {
            float beta = scal[1];
            float l0 = beta * cosb[tid], l1 = beta * cosb[tid + 64];
            float mx = fmaxf(l0, l1);
            #pragma unroll
            for (int o = 32; o >= 1; o >>= 1) mx = fmaxf(mx, __shfl_xor(mx, o));
            float e0 = expf(l0 - mx), e1 = expf(l1 - mx);
            float s = e0 + e1;
            #pragma unroll
            for (int o = 32; o >= 1; o >>= 1) s += __shfl_xor(s, o);
            float inv = 1.0f / s;
            wb[tid] = e0 * inv;
            wb[tid + 64] = e1 * inv;
        }
        __syncthreads();
        {
            int j = tid & 127, hf = tid >> 7;
            float p = 0.f;
            #pragma unroll 8
            for (int r = 0; r < 64; ++r) p = fmaf(wb[hf * 64 + r], M[hf * 64 + r][j], p);
            part[hf * 128 + j] = p;
        }
        __syncthreads();
        if (tid < 128) readv[tid] = part[tid] + part[128 + tid];
        {
            int rr = tid >> 1, hh = tid & 1;
            float wr = wb[rr];
            #pragma unroll 8
            for (int i = 0; i < 64; ++i) {
                int j = hh * 64 + i;
                float m = M[rr][j];
                M[rr][j] = fmaf(-wr, fmaf(ev[j], m, -av[j]), m);
            }
        }
        __syncthreads();
    }

    out[g * NCTRL + tid] = ctrlB[tid];
    if (tid < NWORD) out[NB * NCTRL + g * NWORD + tid] = readv[tid];
}

extern "C" void kernel_launch(void* const* d_in, const int* in_sizes, int n_in,
                              void* d_out, int out_size, void* d_ws, size_t ws_size,
                              hipStream_t stream)
{
    const float* data       = (const float*)d_in[0];
    const int*  batch_sizes = (const int*)d_in[1];
    const int*  unsort      = (const int*)d_in[2];
    float* out = (float*)d_out;

    if (ws_size >= (size_t)WS_FLOATS * sizeof(float)) {
        float* ws = (float*)d_ws;
        prep_kernel<<<(WS_FLOATS + 255) / 256, 256, 0, stream>>>(
            (const float*)d_in[3], (const float*)d_in[4], (const float*)d_in[5],
            (const float*)d_in[6], (const float*)d_in[7], (const float*)d_in[8],
            (const float*)d_in[9], (const float*)d_in[10], (const float*)d_in[11],
            (const float*)d_in[12], (const float*)d_in[13], (const float*)d_in[14], ws);
        ntm4<<<NB / G, 256, 0, stream>>>(data, batch_sizes, unsort,
                                         (const float*)d_in[15], ws, out);
    } else {
        ntm_slow<<<NB, 256, 0, stream>>>(
            data, batch_sizes, unsort,
            (const float*)d_in[3], (const float*)d_in[4], (const float*)d_in[5],
            (const float*)d_in[6], (const float*)d_in[7], (const float*)d_in[8],
            (const float*)d_in[9], (const float*)d_in[10], (const float*)d_in[11],
            (const float*)d_in[12], (const float*)d_in[13], (const float*)d_in[14],
            (const float*)d_in[15], out);
    }
}